// Round 1
// baseline (546.751 us; speedup 1.0000x reference)
//
#include <hip/hip_runtime.h>
#include <hip/hip_bf16.h>

// SAGE reranker: out = a*rer + (1-a)*MLP(relu(conv1)+h) where h = relu(conv0)+x@Wp+bp
// Strategy: project-then-aggregate (linearity of mean), CSR pull aggregation (no float atomics),
// fp32 tiled SGEMM (64x64x16 tile, 4x4 microtile). Workspace: ~106 MB.

#define DIN 256
#define DH 128

// ---------------- CSR build ----------------
__global__ __launch_bounds__(256) void degree_kernel(const int* __restrict__ dst, int E, int* __restrict__ deg){
  int e = blockIdx.x*256 + threadIdx.x;
  if (e < E) atomicAdd(&deg[dst[e]], 1);
}

__global__ __launch_bounds__(256) void bsum_kernel(const int* __restrict__ deg, int n, int* __restrict__ bsum){
  int base = blockIdx.x * 1024;
  int t = threadIdx.x;
  int i = base + t*4;
  int s = 0;
  #pragma unroll
  for (int j=0;j<4;j++) if (i+j < n) s += deg[i+j];
  __shared__ int sh[256];
  sh[t] = s; __syncthreads();
  for (int st=128; st>0; st>>=1){ if (t<st) sh[t]+=sh[t+st]; __syncthreads(); }
  if (t==0) bsum[blockIdx.x]=sh[0];
}

// inclusive scan of <=64 block sums in one wave; also writes off[n]=E
__global__ void scan_bsum_kernel(int* __restrict__ bsum, int nb, int* __restrict__ off, int n, int E){
  int lane = threadIdx.x;  // 64 threads
  int v = (lane < nb)? bsum[lane] : 0;
  #pragma unroll
  for (int s=1; s<64; s<<=1){
    int t = __shfl_up(v, s);
    if (lane >= s) v += t;
  }
  if (lane < nb) bsum[lane] = v;  // inclusive
  if (lane == 0) off[n] = E;
}

__global__ __launch_bounds__(256) void scan_write_kernel(const int* __restrict__ deg, const int* __restrict__ bsum,
                                  int* __restrict__ off, int* __restrict__ cur, int n){
  int blk = blockIdx.x;
  int base = blk*1024;
  int t = threadIdx.x;
  int i = base + t*4;
  int v[4]; int s = 0;
  #pragma unroll
  for (int j=0;j<4;j++){ v[j] = (i+j<n)? deg[i+j] : 0; s += v[j]; }
  __shared__ int sh[256];
  sh[t] = s; __syncthreads();
  for (int st=1; st<256; st<<=1){
    int add = (t>=st)? sh[t-st] : 0;
    __syncthreads();
    sh[t] += add;
    __syncthreads();
  }
  int excl = sh[t] - s;
  int prefix = ((blk==0)? 0 : bsum[blk-1]) + excl;
  #pragma unroll
  for (int j=0;j<4;j++){
    if (i+j < n){ off[i+j] = prefix; cur[i+j] = prefix; }
    prefix += v[j];
  }
}

__global__ __launch_bounds__(256) void fill_kernel(const int* __restrict__ src, const int* __restrict__ dst, int E,
                            int* __restrict__ cur, int* __restrict__ adj){
  int e = blockIdx.x*256 + threadIdx.x;
  if (e < E){
    int p = atomicAdd(&cur[dst[e]], 1);
    adj[p] = src[e];
  }
}

// ---------------- fp32 tiled GEMM: Y_m = X @ W_m (+bias_m) (+relu_m), m selected by blockIdx.y ----
// 64x64 output tile, BK=16, 256 threads, 4x4 microtile/thread.
__global__ __launch_bounds__(256) void gemm_multi(
    const float* __restrict__ X, int nrows, int K, int ncols, int ncb,
    const float* __restrict__ W0, const float* __restrict__ B0, float* __restrict__ Y0, int r0,
    const float* __restrict__ W1, const float* __restrict__ B1, float* __restrict__ Y1, int r1,
    const float* __restrict__ W2, const float* __restrict__ B2, float* __restrict__ Y2, int r2)
{
  int mat = blockIdx.y / ncb;
  int cb  = blockIdx.y % ncb;
  const float* Wm = (mat==0)? W0 : (mat==1)? W1 : W2;
  const float* Bm = (mat==0)? B0 : (mat==1)? B1 : B2;
  float* Ym       = (mat==0)? Y0 : (mat==1)? Y1 : Y2;
  int relu        = (mat==0)? r0 : (mat==1)? r1 : r2;
  int row0 = blockIdx.x * 64;
  int col0 = cb * 64;
  int tid = threadIdx.x;
  __shared__ float As[16][64];   // [k][m], transposed A tile
  __shared__ float Bs[16][64];   // [k][c]
  int tx = tid & 15, ty = tid >> 4;
  float acc[4][4] = {{0.f}};
  // A staging: thread loads float4 along k for one row
  int a_r = tid >> 2;            // 0..63
  int a_k = (tid & 3) * 4;       // 0,4,8,12
  int ga_row = row0 + a_r; if (ga_row >= nrows) ga_row = nrows - 1;  // clamp; stores guarded
  const float* Xp = X + (size_t)ga_row * K + a_k;
  // B staging: thread loads float4 along cols for one k-row
  int b_k = tid >> 4;            // 0..15
  int b_c = (tid & 15) * 4;      // 0..60
  const float* Wq = Wm + (size_t)b_k * ncols + col0 + b_c;
  for (int k0 = 0; k0 < K; k0 += 16){
    float4 av = *(const float4*)(Xp + k0);
    float4 bv = *(const float4*)(Wq + (size_t)k0 * ncols);
    __syncthreads();
    As[a_k+0][a_r] = av.x;
    As[a_k+1][a_r] = av.y;
    As[a_k+2][a_r] = av.z;
    As[a_k+3][a_r] = av.w;
    *(float4*)&Bs[b_k][b_c] = bv;
    __syncthreads();
    #pragma unroll
    for (int kk=0; kk<16; kk++){
      float4 a4 = *(const float4*)&As[kk][ty*4];
      float4 b4 = *(const float4*)&Bs[kk][tx*4];
      float aa[4] = {a4.x,a4.y,a4.z,a4.w};
      float bb[4] = {b4.x,b4.y,b4.z,b4.w};
      #pragma unroll
      for (int i=0;i<4;i++)
        #pragma unroll
        for (int j=0;j<4;j++)
          acc[i][j] = fmaf(aa[i], bb[j], acc[i][j]);
    }
  }
  float4 badd = make_float4(0.f,0.f,0.f,0.f);
  if (Bm) badd = *(const float4*)(Bm + col0 + tx*4);
  #pragma unroll
  for (int i=0;i<4;i++){
    int r = row0 + ty*4 + i;
    if (r < nrows){
      float4 o;
      o.x = acc[i][0] + badd.x;
      o.y = acc[i][1] + badd.y;
      o.z = acc[i][2] + badd.z;
      o.w = acc[i][3] + badd.w;
      if (relu){
        o.x = fmaxf(o.x,0.f); o.y = fmaxf(o.y,0.f);
        o.z = fmaxf(o.z,0.f); o.w = fmaxf(o.w,0.f);
      }
      *(float4*)(Ym + (size_t)r*ncols + col0 + tx*4) = o;
    }
  }
}

// ---------------- pull aggregation + combine: out = relu(mean_agg + bias + root) + residual ----
// 2 nodes per 256-thread block; thread d of a node owns dim d. 4x unrolled gather for MLP latency.
__global__ __launch_bounds__(256) void combine_kernel(
    const float* __restrict__ aggsrc, const float* __restrict__ rootsrc,
    const float* __restrict__ ressrc, const float* __restrict__ bias,
    const int* __restrict__ off, const int* __restrict__ adj,
    float* __restrict__ out, int n)
{
  int t = threadIdx.x;
  int ln = t >> 7;
  int d = t & 127;
  int node = blockIdx.x*2 + ln;
  if (node >= n) return;
  int s = off[node], e = off[node+1];
  float acc = 0.f;
  int p = s;
  for (; p+4 <= e; p += 4){
    int j0 = adj[p], j1 = adj[p+1], j2 = adj[p+2], j3 = adj[p+3];
    float v0 = aggsrc[(size_t)j0*DH + d];
    float v1 = aggsrc[(size_t)j1*DH + d];
    float v2 = aggsrc[(size_t)j2*DH + d];
    float v3 = aggsrc[(size_t)j3*DH + d];
    acc += (v0+v1) + (v2+v3);
  }
  for (; p < e; p++) acc += aggsrc[(size_t)adj[p]*DH + d];
  int cnt = e - s;
  float mean = acc / (float)((cnt>1)?cnt:1);
  float v = mean + bias[d] + rootsrc[(size_t)node*DH + d];
  out[(size_t)node*DH + d] = fmaxf(v, 0.f) + ressrc[(size_t)node*DH + d];
}

// ---------------- final: out = a*rer + (1-a)*(s1 @ W2 + b2), one wave per node ----------------
__global__ __launch_bounds__(256) void final_kernel(
    const float* __restrict__ s1, const float* __restrict__ W2, const float* __restrict__ b2,
    const float* __restrict__ alpha_logit, const float* __restrict__ rer,
    float* __restrict__ out, int n)
{
  int t = threadIdx.x;
  int lane = t & 63;
  int w = t >> 6;
  int node = blockIdx.x*4 + w;
  if (node >= n) return;
  float v = s1[(size_t)node*64 + lane] * W2[lane];
  #pragma unroll
  for (int s=32; s>0; s>>=1) v += __shfl_down(v, s);
  if (lane == 0){
    float al = alpha_logit[0];
    float a = 1.f / (1.f + __expf(-al));
    out[node] = a * rer[node] + (1.f - a) * (v + b2[0]);
  }
}

extern "C" void kernel_launch(void* const* d_in, const int* in_sizes, int n_in,
                              void* d_out, int out_size, void* d_ws, size_t ws_size,
                              hipStream_t stream)
{
  (void)n_in; (void)out_size; (void)ws_size;
  const float* x    = (const float*)d_in[0];
  const int*   ei   = (const int*)d_in[1];
  const float* rer  = (const float*)d_in[2];
  const float* Wp   = (const float*)d_in[3];
  const float* bp   = (const float*)d_in[4];
  const float* Wl0  = (const float*)d_in[5];
  const float* bl0  = (const float*)d_in[6];
  const float* Wr0  = (const float*)d_in[7];
  const float* Wl1  = (const float*)d_in[8];
  const float* bl1  = (const float*)d_in[9];
  const float* Wr1  = (const float*)d_in[10];
  const float* W1   = (const float*)d_in[11];
  const float* b1   = (const float*)d_in[12];
  const float* W2   = (const float*)d_in[13];
  const float* b2   = (const float*)d_in[14];
  const float* alogit = (const float*)d_in[15];

  const int N = in_sizes[2];      // 50000
  const int E = in_sizes[1] / 2;  // 800000
  const int* src = ei;
  const int* dst = ei + E;

  // workspace layout (floats then ints), ~106 MB total
  float* F = (float*)d_ws;
  float* xp  = F;                          // [N][DH]  residual; reused as h2
  float* xl0 = F + (size_t)N*DH;           // reused as hl1, then s1
  float* xr0 = F + (size_t)2*N*DH;         // reused as hr1
  float* h   = F + (size_t)3*N*DH;
  int* I = (int*)(F + (size_t)4*N*DH);
  int* deg  = I;               // N
  int* off  = I + N;           // N+1
  int* cur  = off + (N+1);     // N
  int* bsum = cur + N;         // 64
  int* adj  = bsum + 64;       // E

  hipMemsetAsync(deg, 0, (size_t)N*sizeof(int), stream);
  int gE = (E + 255)/256;
  degree_kernel<<<gE, 256, 0, stream>>>(dst, E, deg);
  int nb = (N + 1023)/1024;    // 49 (<=64 required by scan_bsum)
  bsum_kernel<<<nb, 256, 0, stream>>>(deg, N, bsum);
  scan_bsum_kernel<<<1, 64, 0, stream>>>(bsum, nb, off, N, E);
  scan_write_kernel<<<nb, 256, 0, stream>>>(deg, bsum, off, cur, N);
  fill_kernel<<<gE, 256, 0, stream>>>(src, dst, E, cur, adj);

  // GEMM0: xp = x@Wp+bp ; xl0 = x@Wl0 ; xr0 = x@Wr0   (bl0 added post-mean in combine)
  dim3 g0((N+63)/64, 6);
  gemm_multi<<<g0, 256, 0, stream>>>(x, N, DIN, DH, 2,
      Wp, bp, xp, 0,  Wl0, nullptr, xl0, 0,  Wr0, nullptr, xr0, 0);
  // h = relu(mean(xl0[nbrs]) + bl0 + xr0) + xp
  combine_kernel<<<(N+1)/2, 256, 0, stream>>>(xl0, xr0, xp, bl0, off, adj, h, N);

  float* hl1 = xl0; float* hr1 = xr0; float* h2 = xp;
  dim3 g1((N+63)/64, 4);
  gemm_multi<<<g1, 256, 0, stream>>>(h, N, DH, DH, 2,
      Wl1, nullptr, hl1, 0,  Wr1, nullptr, hr1, 0,  Wr1, nullptr, hr1, 0);
  // h2 = relu(mean(hl1[nbrs]) + bl1 + hr1) + h
  combine_kernel<<<(N+1)/2, 256, 0, stream>>>(hl1, hr1, h, bl1, off, adj, h2, N);

  // s1 = relu(h2@W1 + b1)   [N][64]
  float* s1 = hl1;
  dim3 g2((N+63)/64, 1);
  gemm_multi<<<g2, 256, 0, stream>>>(h2, N, DH, 64, 1,
      W1, b1, s1, 1,  W1, b1, s1, 1,  W1, b1, s1, 1);
  final_kernel<<<(N+3)/4, 256, 0, stream>>>(s1, W2, b2, alogit, rer, (float*)d_out, N);
}

// Round 2
// 352.305 us; speedup vs baseline: 1.5519x; 1.5519x over previous
//
#include <hip/hip_runtime.h>
#include <hip/hip_bf16.h>

// SAGE reranker, bf16-MFMA version.
// out = a*rer + (1-a)*MLP(h2), h2 = relu(conv1(h))+h, h = relu(conv0(x))+x@Wp+bp
// - project-then-aggregate (mean commutes with linear): gather happens at DH=128 in bf16
// - CSR pull aggregation (no float atomics)
// - all GEMMs via v_mfma_f32_16x16x32_bf16, 128x128 tile, LDS stride-40 padding
// - intermediates bf16 (threshold 5.7e-2 >> bf16 error ~1e-3), accumulation fp32

#define DIN 256
#define DH 128

typedef __attribute__((ext_vector_type(8))) short short8;
typedef __attribute__((ext_vector_type(4))) float float4v;

__device__ inline ushort f2b(float f){
  unsigned u = __float_as_uint(f);
  u = (u + 0x7fffu + ((u >> 16) & 1u)) >> 16;   // round-nearest-even
  return (ushort)u;
}
__device__ inline float blo(unsigned v){ return __uint_as_float(v << 16); }
__device__ inline float bhi(unsigned v){ return __uint_as_float(v & 0xffff0000u); }

// ---------------- CSR build ----------------
__global__ __launch_bounds__(256) void degree_kernel(const int* __restrict__ dst, int E, int* __restrict__ deg){
  int e = blockIdx.x*256 + threadIdx.x;
  if (e < E) atomicAdd(&deg[dst[e]], 1);
}

__global__ __launch_bounds__(256) void bsum_kernel(const int* __restrict__ deg, int n, int* __restrict__ bsum){
  int base = blockIdx.x * 1024;
  int t = threadIdx.x;
  int i = base + t*4;
  int s = 0;
  #pragma unroll
  for (int j=0;j<4;j++) if (i+j < n) s += deg[i+j];
  __shared__ int sh[256];
  sh[t] = s; __syncthreads();
  for (int st=128; st>0; st>>=1){ if (t<st) sh[t]+=sh[t+st]; __syncthreads(); }
  if (t==0) bsum[blockIdx.x]=sh[0];
}

__global__ void scan_bsum_kernel(int* __restrict__ bsum, int nb, int* __restrict__ off, int n, int E){
  int lane = threadIdx.x;  // 64 threads
  int v = (lane < nb)? bsum[lane] : 0;
  #pragma unroll
  for (int s=1; s<64; s<<=1){
    int t = __shfl_up(v, s);
    if (lane >= s) v += t;
  }
  if (lane < nb) bsum[lane] = v;  // inclusive
  if (lane == 0) off[n] = E;
}

__global__ __launch_bounds__(256) void scan_write_kernel(const int* __restrict__ deg, const int* __restrict__ bsum,
                                  int* __restrict__ off, int* __restrict__ cur, int n){
  int blk = blockIdx.x;
  int base = blk*1024;
  int t = threadIdx.x;
  int i = base + t*4;
  int v[4]; int s = 0;
  #pragma unroll
  for (int j=0;j<4;j++){ v[j] = (i+j<n)? deg[i+j] : 0; s += v[j]; }
  __shared__ int sh[256];
  sh[t] = s; __syncthreads();
  for (int st=1; st<256; st<<=1){
    int add = (t>=st)? sh[t-st] : 0;
    __syncthreads();
    sh[t] += add;
    __syncthreads();
  }
  int excl = sh[t] - s;
  int prefix = ((blk==0)? 0 : bsum[blk-1]) + excl;
  #pragma unroll
  for (int j=0;j<4;j++){
    if (i+j < n){ off[i+j] = prefix; cur[i+j] = prefix; }
    prefix += v[j];
  }
}

__global__ __launch_bounds__(256) void fill_kernel(const int* __restrict__ src, const int* __restrict__ dst, int E,
                            int* __restrict__ cur, int* __restrict__ adj){
  int e = blockIdx.x*256 + threadIdx.x;
  if (e < E){
    int p = atomicAdd(&cur[dst[e]], 1);
    adj[p] = src[e];
  }
}

// ---------------- conversions ----------------
__global__ __launch_bounds__(256) void convert_x_kernel(const float* __restrict__ x, ushort* __restrict__ xb, int n8){
  int i = blockIdx.x*256 + threadIdx.x;
  if (i >= n8) return;
  size_t o = (size_t)i * 8;
  float4 a = *(const float4*)(x + o);
  float4 b = *(const float4*)(x + o + 4);
  short8 v;
  v[0]=(short)f2b(a.x); v[1]=(short)f2b(a.y); v[2]=(short)f2b(a.z); v[3]=(short)f2b(a.w);
  v[4]=(short)f2b(b.x); v[5]=(short)f2b(b.y); v[6]=(short)f2b(b.z); v[7]=(short)f2b(b.w);
  *(short8*)(xb + o) = v;
}

// convert + transpose weights: dst[c][r] = bf16(src[r][c])
__global__ __launch_bounds__(256) void prep_w_kernel(
    const float* __restrict__ Wp, const float* __restrict__ Wl0, const float* __restrict__ Wr0,
    const float* __restrict__ Wl1, const float* __restrict__ Wr1, const float* __restrict__ W1,
    ushort* __restrict__ Wpt, ushort* __restrict__ Wl0t, ushort* __restrict__ Wr0t,
    ushort* __restrict__ Wl1t, ushort* __restrict__ Wr1t, ushort* __restrict__ W1t)
{
  const float* src; ushort* dst; int rows, cols;
  switch (blockIdx.y){
    case 0: src=Wp;  dst=Wpt;  rows=256; cols=128; break;
    case 1: src=Wl0; dst=Wl0t; rows=256; cols=128; break;
    case 2: src=Wr0; dst=Wr0t; rows=256; cols=128; break;
    case 3: src=Wl1; dst=Wl1t; rows=128; cols=128; break;
    case 4: src=Wr1; dst=Wr1t; rows=128; cols=128; break;
    default:src=W1;  dst=W1t;  rows=128; cols=64;  break;
  }
  int idx = blockIdx.x*256 + threadIdx.x;
  if (idx >= rows*cols) return;
  int r = idx / cols, c = idx - r*cols;
  dst[c*rows + r] = f2b(src[idx]);
}

// ---------------- bf16 MFMA GEMM: Y = A @ W (+bias)(+relu), mat by blockIdx.y ----------------
// A: [nrows][K] bf16 (raw ushort). W: [NCOLS][K] bf16 pre-transposed. 128x128 block tile,
// 4 waves, each wave 32 rows x NCOLS cols via 16x16x32 MFMA. LDS stride 40 (pad) for frag reads.
template<int K, int NCOLS, bool OUTBF>
__global__ __launch_bounds__(256) void gemm_mfma(
    const ushort* __restrict__ A, int nrows,
    const ushort* __restrict__ W0, const float* __restrict__ B0, void* __restrict__ Y0, int r0,
    const ushort* __restrict__ W1, const float* __restrict__ B1, void* __restrict__ Y1, int r1,
    const ushort* __restrict__ W2, const float* __restrict__ B2, void* __restrict__ Y2, int r2)
{
  constexpr int NT = NCOLS / 16;
  int mat = blockIdx.y;
  const ushort* Wm = (mat==0)? W0 : (mat==1)? W1 : W2;
  const float*  Bm = (mat==0)? B0 : (mat==1)? B1 : B2;
  void* Ym         = (mat==0)? Y0 : (mat==1)? Y1 : Y2;
  int relu         = (mat==0)? r0 : (mat==1)? r1 : r2;

  __shared__ __align__(16) ushort As[128][40];
  __shared__ __align__(16) ushort Bs[NCOLS][40];

  int t = threadIdx.x;
  int w = t >> 6;
  int lane = t & 63;
  int lq = lane & 15;
  int quad = lane >> 4;
  int qk = quad * 8;

  int row0 = blockIdx.x * 128;
  // A staging: 2 threads per row, 16 elems (32B) each
  int ar = t >> 1, akp = (t & 1) * 16;
  int garow = row0 + ar; if (garow >= nrows) garow = nrows - 1;
  const ushort* Ap = A + (size_t)garow * K + akp;
  // B staging
  int bc, bkp;
  if (NCOLS == 128){ bc = t >> 1; bkp = (t & 1) * 16; }
  else             { bc = t >> 2; bkp = (t & 3) * 8;  }
  const ushort* Wq = Wm + (size_t)bc * K + bkp;

  float4v acc[2][NT];
  #pragma unroll
  for (int i=0;i<2;i++)
    #pragma unroll
    for (int j=0;j<NT;j++)
      #pragma unroll
      for (int r=0;r<4;r++) acc[i][j][r] = 0.f;

  #pragma unroll
  for (int k0 = 0; k0 < K; k0 += 32){
    short8 av0 = *(const short8*)(Ap + k0);
    short8 av1 = *(const short8*)(Ap + k0 + 8);
    short8 bv0, bv1;
    bv0 = *(const short8*)(Wq + k0);
    if (NCOLS == 128) bv1 = *(const short8*)(Wq + k0 + 8);
    __syncthreads();
    *(short8*)&As[ar][akp]     = av0;
    *(short8*)&As[ar][akp + 8] = av1;
    *(short8*)&Bs[bc][bkp] = bv0;
    if (NCOLS == 128) *(short8*)&Bs[bc][bkp + 8] = bv1;
    __syncthreads();
    short8 af0 = *(const short8*)&As[w*32 + lq][qk];
    short8 af1 = *(const short8*)&As[w*32 + 16 + lq][qk];
    #pragma unroll
    for (int nt=0; nt<NT; nt++){
      short8 bf = *(const short8*)&Bs[nt*16 + lq][qk];
      acc[0][nt] = __builtin_amdgcn_mfma_f32_16x16x32_bf16(af0, bf, acc[0][nt], 0,0,0);
      acc[1][nt] = __builtin_amdgcn_mfma_f32_16x16x32_bf16(af1, bf, acc[1][nt], 0,0,0);
    }
  }

  float bias[NT];
  #pragma unroll
  for (int nt=0; nt<NT; nt++) bias[nt] = Bm ? Bm[nt*16 + lq] : 0.f;
  #pragma unroll
  for (int mt=0; mt<2; mt++){
    #pragma unroll
    for (int r=0; r<4; r++){
      int row = row0 + w*32 + mt*16 + quad*4 + r;
      if (row < nrows){
        #pragma unroll
        for (int nt=0; nt<NT; nt++){
          float v = acc[mt][nt][r] + bias[nt];
          if (relu) v = fmaxf(v, 0.f);
          if (OUTBF) ((ushort*)Ym)[(size_t)row*NCOLS + nt*16 + lq] = f2b(v);
          else       ((float*) Ym)[(size_t)row*NCOLS + nt*16 + lq] = v;
        }
      }
    }
  }
}

// ---------------- combine (bf16): out = bf16(relu(mean_agg + bias + root) + res) ----------------
// one wave per node; lane d owns dims {2d, 2d+1} as packed bf16x2 (uint)
__global__ __launch_bounds__(256) void combine_b_kernel(
    const ushort* __restrict__ aggsrc, const ushort* __restrict__ rootsrc,
    const ushort* __restrict__ ressrc, const float* __restrict__ bias,
    const int* __restrict__ off, const int* __restrict__ adj,
    ushort* __restrict__ out, int n)
{
  int t = threadIdx.x;
  int d = t & 63;
  int node = blockIdx.x*4 + (t >> 6);
  if (node >= n) return;
  int s = off[node], e = off[node+1];
  const unsigned* aggu = (const unsigned*)aggsrc;
  float a0 = 0.f, a1 = 0.f;
  int p = s;
  for (; p+4 <= e; p += 4){
    int j0 = adj[p], j1 = adj[p+1], j2 = adj[p+2], j3 = adj[p+3];
    unsigned v0 = aggu[(size_t)j0*64 + d];
    unsigned v1 = aggu[(size_t)j1*64 + d];
    unsigned v2 = aggu[(size_t)j2*64 + d];
    unsigned v3 = aggu[(size_t)j3*64 + d];
    a0 += (blo(v0)+blo(v1)) + (blo(v2)+blo(v3));
    a1 += (bhi(v0)+bhi(v1)) + (bhi(v2)+bhi(v3));
  }
  for (; p < e; p++){
    unsigned v = aggu[(size_t)adj[p]*64 + d];
    a0 += blo(v); a1 += bhi(v);
  }
  int cnt = e - s;
  float inv = 1.f / (float)((cnt > 1)? cnt : 1);
  unsigned rt = ((const unsigned*)rootsrc)[(size_t)node*64 + d];
  unsigned rs = ((const unsigned*)ressrc)[(size_t)node*64 + d];
  float o0 = fmaxf(a0*inv + bias[2*d]   + blo(rt), 0.f) + blo(rs);
  float o1 = fmaxf(a1*inv + bias[2*d+1] + bhi(rt), 0.f) + bhi(rs);
  ((unsigned*)out)[(size_t)node*64 + d] = (unsigned)f2b(o0) | ((unsigned)f2b(o1) << 16);
}

// ---------------- final: out = a*rer + (1-a)*(s1 @ W2 + b2) ----------------
__global__ __launch_bounds__(256) void final_kernel(
    const float* __restrict__ s1, const float* __restrict__ W2, const float* __restrict__ b2,
    const float* __restrict__ alpha_logit, const float* __restrict__ rer,
    float* __restrict__ out, int n)
{
  int t = threadIdx.x;
  int lane = t & 63;
  int w = t >> 6;
  int node = blockIdx.x*4 + w;
  if (node >= n) return;
  float v = s1[(size_t)node*64 + lane] * W2[lane];
  #pragma unroll
  for (int s=32; s>0; s>>=1) v += __shfl_down(v, s);
  if (lane == 0){
    float al = alpha_logit[0];
    float a = 1.f / (1.f + __expf(-al));
    out[node] = a * rer[node] + (1.f - a) * (v + b2[0]);
  }
}

extern "C" void kernel_launch(void* const* d_in, const int* in_sizes, int n_in,
                              void* d_out, int out_size, void* d_ws, size_t ws_size,
                              hipStream_t stream)
{
  (void)n_in; (void)out_size; (void)ws_size;
  const float* x    = (const float*)d_in[0];
  const int*   ei   = (const int*)d_in[1];
  const float* rer  = (const float*)d_in[2];
  const float* Wp   = (const float*)d_in[3];
  const float* bp   = (const float*)d_in[4];
  const float* Wl0  = (const float*)d_in[5];
  const float* bl0  = (const float*)d_in[6];
  const float* Wr0  = (const float*)d_in[7];
  const float* Wl1  = (const float*)d_in[8];
  const float* bl1  = (const float*)d_in[9];
  const float* Wr1  = (const float*)d_in[10];
  const float* W1   = (const float*)d_in[11];
  const float* b1   = (const float*)d_in[12];
  const float* W2   = (const float*)d_in[13];
  const float* b2   = (const float*)d_in[14];
  const float* alogit = (const float*)d_in[15];

  const int N = in_sizes[2];      // 50000
  const int E = in_sizes[1] / 2;  // 800000
  const int* src = ei;
  const int* dst = ei + E;

  // workspace: bf16 buffers then weights then ints (~81 MB)
  ushort* U = (ushort*)d_ws;
  ushort* xb  = U;                         // [N][256] bf16
  ushort* xp  = xb  + (size_t)N*DIN;       // [N][128] residual; reused as h2
  ushort* xl0 = xp  + (size_t)N*DH;        // reused as hl1
  ushort* xr0 = xl0 + (size_t)N*DH;        // reused as hr1
  ushort* h   = xr0 + (size_t)N*DH;        // reused as s1 (fp32 [N][64])
  ushort* Wpt  = h    + (size_t)N*DH;
  ushort* Wl0t = Wpt  + 256*128;
  ushort* Wr0t = Wl0t + 256*128;
  ushort* Wl1t = Wr0t + 256*128;
  ushort* Wr1t = Wl1t + 128*128;
  ushort* W1t  = Wr1t + 128*128;
  int* I    = (int*)(W1t + 128*64);
  int* deg  = I;               // N
  int* off  = I + N;           // N+1
  int* cur  = off + (N+1);     // N
  int* bsum = cur + N;         // 64
  int* adj  = bsum + 64;       // E

  // conversions (independent of CSR)
  prep_w_kernel<<<dim3(128,6), 256, 0, stream>>>(Wp,Wl0,Wr0,Wl1,Wr1,W1, Wpt,Wl0t,Wr0t,Wl1t,Wr1t,W1t);
  convert_x_kernel<<<((N*DIN/8)+255)/256, 256, 0, stream>>>(x, xb, N*DIN/8);

  // CSR build
  hipMemsetAsync(deg, 0, (size_t)N*sizeof(int), stream);
  int gE = (E + 255)/256;
  degree_kernel<<<gE, 256, 0, stream>>>(dst, E, deg);
  int nb = (N + 1023)/1024;    // 49 (<=64)
  bsum_kernel<<<nb, 256, 0, stream>>>(deg, N, bsum);
  scan_bsum_kernel<<<1, 64, 0, stream>>>(bsum, nb, off, N, E);
  scan_write_kernel<<<nb, 256, 0, stream>>>(deg, bsum, off, cur, N);
  fill_kernel<<<gE, 256, 0, stream>>>(src, dst, E, cur, adj);

  int gx = (N + 127)/128;
  // GEMM0: xp = x@Wp+bp ; xl0 = x@Wl0 ; xr0 = x@Wr0  (bl0 added post-mean)
  gemm_mfma<256,128,true><<<dim3(gx,3), 256, 0, stream>>>(xb, N,
      Wpt, bp, xp, 0,  Wl0t, nullptr, xl0, 0,  Wr0t, nullptr, xr0, 0);
  // h = relu(mean(xl0[nbrs]) + bl0 + xr0) + xp
  combine_b_kernel<<<(N+3)/4, 256, 0, stream>>>(xl0, xr0, xp, bl0, off, adj, h, N);

  // GEMM1: hl1 = h@Wl1 ; hr1 = h@Wr1   (reuse xl0/xr0)
  gemm_mfma<128,128,true><<<dim3(gx,2), 256, 0, stream>>>(h, N,
      Wl1t, nullptr, xl0, 0,  Wr1t, nullptr, xr0, 0,  Wr1t, nullptr, xr0, 0);
  // h2 = relu(mean(hl1[nbrs]) + bl1 + hr1) + h   (h2 -> xp)
  combine_b_kernel<<<(N+3)/4, 256, 0, stream>>>(xl0, xr0, h, bl1, off, adj, xp, N);

  // s1 = relu(h2@W1 + b1)  fp32 [N][64]  (into h's buffer)
  float* s1 = (float*)h;
  gemm_mfma<128,64,false><<<dim3(gx,1), 256, 0, stream>>>(xp, N,
      W1t, b1, (void*)s1, 1,  W1t, b1, (void*)s1, 1,  W1t, b1, (void*)s1, 1);
  final_kernel<<<(N+3)/4, 256, 0, stream>>>(s1, W2, b2, alogit, rer, (float*)d_out, N);
}

// Round 3
// 294.021 us; speedup vs baseline: 1.8596x; 1.1982x over previous
//
#include <hip/hip_runtime.h>
#include <hip/hip_bf16.h>

// SAGE reranker, bf16-MFMA + bucketed-CSR version.
// Round-3 changes vs round 2:
//  - CSR build rewritten: bucket (dst>>9) partition with LDS staging; ALL global
//    writes coalesced (round-2 fill_kernel did 800K scattered 4B stores -> 52MB
//    HBM write amplification, 52us).
//  - GEMM0 computes Wp/Wl0/Wr0 from one A tile (x read once, fp32->bf16 inline;
//    convert_x deleted). GEMM1 computes Wl1/Wr1 from one A tile.
//  - Head GEMM fuses @W2+b2 dot + alpha mix in epilogue (final_kernel deleted).

#define DIN 256
#define DH 128
#define NPB 512        // nodes per bucket (dst>>9)
#define NBMAX 128      // max buckets (N<=65536)
#define EPB 4096       // edges per partition block
#define CAP 14336      // LDS adj window capacity (bucket edges ~8.2K expected)

typedef __attribute__((ext_vector_type(8))) short short8;
typedef __attribute__((ext_vector_type(4))) float float4v;

__device__ inline ushort f2b(float f){
  unsigned u = __float_as_uint(f);
  u = (u + 0x7fffu + ((u >> 16) & 1u)) >> 16;   // round-nearest-even
  return (ushort)u;
}
__device__ inline float blo(unsigned v){ return __uint_as_float(v << 16); }
__device__ inline float bhi(unsigned v){ return __uint_as_float(v & 0xffff0000u); }

// ---------------- CSR build (bucketed, coalesced writes only) ----------------
__global__ __launch_bounds__(256) void bucket_hist_kernel(
    const int* __restrict__ dst, int E, int NB, int* __restrict__ bucketCnt)
{
  __shared__ int hist[NBMAX];
  int t = threadIdx.x;
  for (int i=t;i<NB;i+=256) hist[i]=0;
  __syncthreads();
  int base = blockIdx.x * EPB;
  #pragma unroll
  for (int j=0;j<16;j++){
    int e = base + j*256 + t;
    if (e < E) atomicAdd(&hist[dst[e] >> 9], 1);
  }
  __syncthreads();
  for (int i=t;i<NB;i+=256) atomicAdd(&bucketCnt[i], hist[i]);
}

__global__ void scan_buckets_kernel(const int* __restrict__ bucketCnt, int NB, int E,
                                    int* __restrict__ bucketBase, int* __restrict__ bucketCur,
                                    int* __restrict__ off, int N)
{
  __shared__ int s[NBMAX];
  int t = threadIdx.x;  // NBMAX threads
  s[t] = (t < NB)? bucketCnt[t] : 0;
  __syncthreads();
  for (int st=1; st<NBMAX; st<<=1){
    int v = (t>=st)? s[t-st] : 0;
    __syncthreads();
    s[t] += v;
    __syncthreads();
  }
  int excl = (t>0)? s[t-1] : 0;
  if (t < NB){ bucketBase[t] = excl; bucketCur[t] = excl; }
  if (t == NB) bucketBase[NB] = E;
  if (t == 0) off[N] = E;   // safety (also written by last bucket_csr block)
}

__global__ __launch_bounds__(256) void partition_kernel(
    const int* __restrict__ src, const int* __restrict__ dst, int E, int NB,
    int* __restrict__ bucketCur, int* __restrict__ pairS, int* __restrict__ pairD)
{
  __shared__ int hist[NBMAX], lbase[NBMAX], gbase[NBMAX], lcur[NBMAX], sc[NBMAX];
  __shared__ int ls[EPB], ld[EPB];
  int t = threadIdx.x;
  int base = blockIdx.x * EPB;
  int cnt = E - base; if (cnt > EPB) cnt = EPB;
  for (int i=t;i<NB;i+=256) hist[i]=0;
  __syncthreads();
  int myS[16], myD[16];
  #pragma unroll
  for (int j=0;j<16;j++){
    int e = base + j*256 + t;
    if (e < E){ myS[j]=src[e]; myD[j]=dst[e]; atomicAdd(&hist[myD[j]>>9],1); }
    else myD[j] = -1;
  }
  __syncthreads();
  if (t < NBMAX) sc[t] = (t < NB)? hist[t] : 0;
  __syncthreads();
  for (int st=1; st<NBMAX; st<<=1){
    int v = 0;
    if (t < NBMAX && t >= st) v = sc[t-st];
    __syncthreads();
    if (t < NBMAX) sc[t] += v;
    __syncthreads();
  }
  if (t < NB){
    int excl = (t>0)? sc[t-1] : 0;
    lbase[t] = excl; lcur[t] = excl;
    gbase[t] = atomicAdd(&bucketCur[t], hist[t]);
  }
  __syncthreads();
  #pragma unroll
  for (int j=0;j<16;j++){
    if (myD[j] >= 0){
      int b = myD[j] >> 9;
      int p = atomicAdd(&lcur[b], 1);
      ls[p] = myS[j]; ld[p] = myD[j];
    }
  }
  __syncthreads();
  for (int i=t;i<cnt;i+=256){
    int d = ld[i];
    int b = d >> 9;
    int pos = gbase[b] + (i - lbase[b]);   // bucket-contiguous coalesced runs
    pairS[pos] = ls[i];
    pairD[pos] = d;
  }
}

__global__ __launch_bounds__(256) void bucket_csr_kernel(
    const int* __restrict__ bucketBase, const int* __restrict__ pairS,
    const int* __restrict__ pairD, int N, int* __restrict__ off, int* __restrict__ adj)
{
  __shared__ int cnt[NPB];
  __shared__ int offl[NPB+1];
  __shared__ int s1[256];
  __shared__ int win[CAP];
  int b = blockIdx.x;
  int t = threadIdx.x;
  int node0 = b * NPB;
  int base = bucketBase[b], end = bucketBase[b+1];
  int ce = end - base;
  for (int i=t;i<NPB;i+=256) cnt[i]=0;
  __syncthreads();
  for (int i=t;i<ce;i+=256) atomicAdd(&cnt[pairD[base+i]-node0], 1);
  __syncthreads();
  int a0 = cnt[2*t], a1 = cnt[2*t+1];
  s1[t] = a0 + a1;
  __syncthreads();
  for (int st=1; st<256; st<<=1){
    int v = (t>=st)? s1[t-st] : 0;
    __syncthreads();
    s1[t] += v;
    __syncthreads();
  }
  int excl = (t>0)? s1[t-1] : 0;
  offl[2*t] = excl; offl[2*t+1] = excl + a0;
  if (t == 255) offl[NPB] = s1[255];
  __syncthreads();
  for (int i=t;i<NPB;i+=256){
    int node = node0 + i;
    if (node <= N) off[node] = base + offl[i];
  }
  __syncthreads();
  // offl reused as cursor
  if (ce <= CAP){
    for (int i=t;i<ce;i+=256){
      int d = pairD[base+i];
      int p = atomicAdd(&offl[d-node0], 1);
      win[p] = pairS[base+i];          // LDS scatter: random ~2-way, free
    }
    __syncthreads();
    for (int i=t;i<ce;i+=256) adj[base+i] = win[i];   // coalesced dump
  } else {
    for (int i=t;i<ce;i+=256){
      int d = pairD[base+i];
      int p = atomicAdd(&offl[d-node0], 1);
      adj[base+p] = pairS[base+i];     // overflow fallback (never for this input)
    }
  }
}

// ---------------- weight prep: dst[c][r] = bf16(src[r][c]) ----------------
__global__ __launch_bounds__(256) void prep_w_kernel(
    const float* __restrict__ Wp, const float* __restrict__ Wl0, const float* __restrict__ Wr0,
    const float* __restrict__ Wl1, const float* __restrict__ Wr1, const float* __restrict__ W1,
    ushort* __restrict__ Wpt, ushort* __restrict__ Wl0t, ushort* __restrict__ Wr0t,
    ushort* __restrict__ Wl1t, ushort* __restrict__ Wr1t, ushort* __restrict__ W1t)
{
  const float* src; ushort* dst; int rows, cols;
  switch (blockIdx.y){
    case 0: src=Wp;  dst=Wpt;  rows=256; cols=128; break;
    case 1: src=Wl0; dst=Wl0t; rows=256; cols=128; break;
    case 2: src=Wr0; dst=Wr0t; rows=256; cols=128; break;
    case 3: src=Wl1; dst=Wl1t; rows=128; cols=128; break;
    case 4: src=Wr1; dst=Wr1t; rows=128; cols=128; break;
    default:src=W1;  dst=W1t;  rows=128; cols=64;  break;
  }
  int idx = blockIdx.x*256 + threadIdx.x;
  if (idx >= rows*cols) return;
  int r = idx / cols, c = idx - r*cols;
  dst[c*rows + r] = f2b(src[idx]);
}

// ---------------- multi-output bf16 MFMA GEMM: Ym = A @ Wm (+bias on mat0) ----------------
// 128 rows x 128 cols x NMAT mats per block; A read ONCE. A fp32 (converted inline) or bf16.
template<int K, int NMAT, bool AFP32>
__global__ __launch_bounds__(256,2) void gemm_mfma_multi(
    const void* __restrict__ Av, int nrows,
    const ushort* __restrict__ Wt0, const ushort* __restrict__ Wt1, const ushort* __restrict__ Wt2,
    const float* __restrict__ bias0,
    ushort* __restrict__ Y0, ushort* __restrict__ Y1, ushort* __restrict__ Y2)
{
  __shared__ __align__(16) ushort As[128][40];
  __shared__ __align__(16) ushort Bs[NMAT][128][40];
  int t = threadIdx.x;
  int w = t>>6, lane = t&63, lq = lane&15, quad = lane>>4, qk = quad*8;
  int row0 = blockIdx.x*128;
  int ar = t>>1, akp = (t&1)*16;
  int garow = row0 + ar; if (garow >= nrows) garow = nrows - 1;
  const float*  Af = (const float*)Av;
  const ushort* Ab = (const ushort*)Av;
  int bc = t>>1, bkp = (t&1)*16;

  float4v acc[NMAT][2][8];
  #pragma unroll
  for (int m=0;m<NMAT;m++)
    #pragma unroll
    for (int i=0;i<2;i++)
      #pragma unroll
      for (int j=0;j<8;j++)
        #pragma unroll
        for (int r=0;r<4;r++) acc[m][i][j][r] = 0.f;

  for (int k0=0; k0<K; k0+=32){
    short8 av0, av1;
    if (AFP32){
      const float* p = Af + (size_t)garow*K + akp + k0;
      float4 f0 = *(const float4*)(p);
      float4 f1 = *(const float4*)(p+4);
      float4 f2 = *(const float4*)(p+8);
      float4 f3 = *(const float4*)(p+12);
      av0[0]=(short)f2b(f0.x); av0[1]=(short)f2b(f0.y); av0[2]=(short)f2b(f0.z); av0[3]=(short)f2b(f0.w);
      av0[4]=(short)f2b(f1.x); av0[5]=(short)f2b(f1.y); av0[6]=(short)f2b(f1.z); av0[7]=(short)f2b(f1.w);
      av1[0]=(short)f2b(f2.x); av1[1]=(short)f2b(f2.y); av1[2]=(short)f2b(f2.z); av1[3]=(short)f2b(f2.w);
      av1[4]=(short)f2b(f3.x); av1[5]=(short)f2b(f3.y); av1[6]=(short)f2b(f3.z); av1[7]=(short)f2b(f3.w);
    } else {
      const ushort* p = Ab + (size_t)garow*K + akp + k0;
      av0 = *(const short8*)p;
      av1 = *(const short8*)(p+8);
    }
    short8 bv0[NMAT], bv1[NMAT];
    #pragma unroll
    for (int m=0;m<NMAT;m++){
      const ushort* Wm = (m==0)? Wt0 : (m==1)? Wt1 : Wt2;
      const ushort* p = Wm + (size_t)bc*K + bkp + k0;
      bv0[m] = *(const short8*)p;
      bv1[m] = *(const short8*)(p+8);
    }
    __syncthreads();
    *(short8*)&As[ar][akp]   = av0;
    *(short8*)&As[ar][akp+8] = av1;
    #pragma unroll
    for (int m=0;m<NMAT;m++){
      *(short8*)&Bs[m][bc][bkp]   = bv0[m];
      *(short8*)&Bs[m][bc][bkp+8] = bv1[m];
    }
    __syncthreads();
    short8 af0 = *(const short8*)&As[w*32 + lq][qk];
    short8 af1 = *(const short8*)&As[w*32 + 16 + lq][qk];
    #pragma unroll
    for (int nt=0; nt<8; nt++){
      #pragma unroll
      for (int m=0;m<NMAT;m++){
        short8 bf = *(const short8*)&Bs[m][nt*16 + lq][qk];
        acc[m][0][nt] = __builtin_amdgcn_mfma_f32_16x16x32_bf16(af0, bf, acc[m][0][nt], 0,0,0);
        acc[m][1][nt] = __builtin_amdgcn_mfma_f32_16x16x32_bf16(af1, bf, acc[m][1][nt], 0,0,0);
      }
    }
  }

  #pragma unroll
  for (int m=0;m<NMAT;m++){
    ushort* Ym = (m==0)? Y0 : (m==1)? Y1 : Y2;
    #pragma unroll
    for (int mt=0; mt<2; mt++){
      #pragma unroll
      for (int r=0; r<4; r++){
        int row = row0 + w*32 + mt*16 + quad*4 + r;
        if (row < nrows){
          #pragma unroll
          for (int nt=0; nt<8; nt++){
            float v = acc[m][mt][nt][r];
            if (m==0 && bias0) v += bias0[nt*16 + lq];
            Ym[(size_t)row*128 + nt*16 + lq] = f2b(v);
          }
        }
      }
    }
  }
}

// ---------------- combine: out = bf16(relu(mean_agg + bias + root) + res) ----------------
__global__ __launch_bounds__(256) void combine_b_kernel(
    const ushort* __restrict__ aggsrc, const ushort* __restrict__ rootsrc,
    const ushort* __restrict__ ressrc, const float* __restrict__ bias,
    const int* __restrict__ off, const int* __restrict__ adj,
    ushort* __restrict__ out, int n)
{
  int t = threadIdx.x;
  int d = t & 63;
  int node = blockIdx.x*4 + (t >> 6);
  if (node >= n) return;
  int s = off[node], e = off[node+1];
  const unsigned* aggu = (const unsigned*)aggsrc;
  float a0 = 0.f, a1 = 0.f;
  int p = s;
  for (; p+4 <= e; p += 4){
    int j0 = adj[p], j1 = adj[p+1], j2 = adj[p+2], j3 = adj[p+3];
    unsigned v0 = aggu[(size_t)j0*64 + d];
    unsigned v1 = aggu[(size_t)j1*64 + d];
    unsigned v2 = aggu[(size_t)j2*64 + d];
    unsigned v3 = aggu[(size_t)j3*64 + d];
    a0 += (blo(v0)+blo(v1)) + (blo(v2)+blo(v3));
    a1 += (bhi(v0)+bhi(v1)) + (bhi(v2)+bhi(v3));
  }
  for (; p < e; p++){
    unsigned v = aggu[(size_t)adj[p]*64 + d];
    a0 += blo(v); a1 += bhi(v);
  }
  int cnt = e - s;
  float inv = 1.f / (float)((cnt > 1)? cnt : 1);
  unsigned rt = ((const unsigned*)rootsrc)[(size_t)node*64 + d];
  unsigned rs = ((const unsigned*)ressrc)[(size_t)node*64 + d];
  float o0 = fmaxf(a0*inv + bias[2*d]   + blo(rt), 0.f) + blo(rs);
  float o1 = fmaxf(a1*inv + bias[2*d+1] + bhi(rt), 0.f) + bhi(rs);
  ((unsigned*)out)[(size_t)node*64 + d] = (unsigned)f2b(o0) | ((unsigned)f2b(o1) << 16);
}

// ---------------- head GEMM fused with W2 dot + alpha mix ----------------
// s1 = relu(A@W1 + b1) [rows][64]; out[row] = a*rer + (1-a)*(s1 . W2 + b2)
__global__ __launch_bounds__(256) void gemm_final_kernel(
    const ushort* __restrict__ A, int nrows,
    const ushort* __restrict__ W1t, const float* __restrict__ b1,
    const float* __restrict__ W2, const float* __restrict__ b2,
    const float* __restrict__ alogit, const float* __restrict__ rer,
    float* __restrict__ out)
{
  __shared__ __align__(16) ushort As[128][40];
  __shared__ __align__(16) ushort Bs[64][40];
  int t = threadIdx.x;
  int w = t>>6, lane = t&63, lq = lane&15, quad = lane>>4, qk = quad*8;
  int row0 = blockIdx.x*128;
  int ar = t>>1, akp = (t&1)*16;
  int garow = row0 + ar; if (garow >= nrows) garow = nrows - 1;
  const ushort* Ap = A + (size_t)garow*128 + akp;
  int bc = t>>2, bkp = (t&3)*8;
  const ushort* Wq = W1t + (size_t)bc*128 + bkp;

  float4v acc[2][4];
  #pragma unroll
  for (int i=0;i<2;i++)
    #pragma unroll
    for (int j=0;j<4;j++)
      #pragma unroll
      for (int r=0;r<4;r++) acc[i][j][r] = 0.f;

  #pragma unroll
  for (int k0=0; k0<128; k0+=32){
    short8 av0 = *(const short8*)(Ap + k0);
    short8 av1 = *(const short8*)(Ap + k0 + 8);
    short8 bv  = *(const short8*)(Wq + k0);
    __syncthreads();
    *(short8*)&As[ar][akp]   = av0;
    *(short8*)&As[ar][akp+8] = av1;
    *(short8*)&Bs[bc][bkp]   = bv;
    __syncthreads();
    short8 af0 = *(const short8*)&As[w*32 + lq][qk];
    short8 af1 = *(const short8*)&As[w*32 + 16 + lq][qk];
    #pragma unroll
    for (int nt=0; nt<4; nt++){
      short8 bf = *(const short8*)&Bs[nt*16 + lq][qk];
      acc[0][nt] = __builtin_amdgcn_mfma_f32_16x16x32_bf16(af0, bf, acc[0][nt], 0,0,0);
      acc[1][nt] = __builtin_amdgcn_mfma_f32_16x16x32_bf16(af1, bf, acc[1][nt], 0,0,0);
    }
  }

  float al = alogit[0];
  float a  = 1.f / (1.f + __expf(-al));
  float pw[2][4] = {{0.f}};
  #pragma unroll
  for (int nt=0; nt<4; nt++){
    int c = nt*16 + lq;
    float w2 = W2[c];
    float bb = b1[c];
    #pragma unroll
    for (int mt=0; mt<2; mt++)
      #pragma unroll
      for (int r=0; r<4; r++)
        pw[mt][r] += fmaxf(acc[mt][nt][r] + bb, 0.f) * w2;
  }
  #pragma unroll
  for (int mask=1; mask<16; mask<<=1){
    #pragma unroll
    for (int mt=0; mt<2; mt++)
      #pragma unroll
      for (int r=0; r<4; r++)
        pw[mt][r] += __shfl_xor(pw[mt][r], mask);
  }
  if (lq == 0){
    #pragma unroll
    for (int mt=0; mt<2; mt++)
      #pragma unroll
      for (int r=0; r<4; r++){
        int row = row0 + w*32 + mt*16 + quad*4 + r;
        if (row < nrows)
          out[row] = a * rer[row] + (1.f - a) * (pw[mt][r] + b2[0]);
      }
  }
}

extern "C" void kernel_launch(void* const* d_in, const int* in_sizes, int n_in,
                              void* d_out, int out_size, void* d_ws, size_t ws_size,
                              hipStream_t stream)
{
  (void)n_in; (void)out_size; (void)ws_size;
  const float* x    = (const float*)d_in[0];
  const int*   ei   = (const int*)d_in[1];
  const float* rer  = (const float*)d_in[2];
  const float* Wp   = (const float*)d_in[3];
  const float* bp   = (const float*)d_in[4];
  const float* Wl0  = (const float*)d_in[5];
  const float* bl0  = (const float*)d_in[6];
  const float* Wr0  = (const float*)d_in[7];
  const float* Wl1  = (const float*)d_in[8];
  const float* bl1  = (const float*)d_in[9];
  const float* Wr1  = (const float*)d_in[10];
  const float* W1   = (const float*)d_in[11];
  const float* b1   = (const float*)d_in[12];
  const float* W2   = (const float*)d_in[13];
  const float* b2   = (const float*)d_in[14];
  const float* alogit = (const float*)d_in[15];

  const int N = in_sizes[2];      // 50000
  const int E = in_sizes[1] / 2;  // 800000
  const int* src = ei;
  const int* dst = ei + E;
  const int NB = (N + NPB - 1) / NPB;   // 98

  // workspace layout
  ushort* U = (ushort*)d_ws;
  ushort* xp  = U;                         // [N][128] residual; reused as h2
  ushort* xl0 = xp  + (size_t)N*DH;        // reused as hl1
  ushort* xr0 = xl0 + (size_t)N*DH;        // reused as hr1
  ushort* h   = xr0 + (size_t)N*DH;
  ushort* Wpt  = h    + (size_t)N*DH;
  ushort* Wl0t = Wpt  + 256*128;
  ushort* Wr0t = Wl0t + 256*128;
  ushort* Wl1t = Wr0t + 256*128;
  ushort* Wr1t = Wl1t + 128*128;
  ushort* W1t  = Wr1t + 128*128;
  int* I = (int*)(W1t + 128*64);
  int* bucketCnt  = I;                   // NBMAX
  int* bucketBase = bucketCnt + NBMAX;   // NBMAX+1
  int* bucketCur  = bucketBase + NBMAX + 1;
  int* off   = bucketCur + NBMAX;        // N+1
  int* pairS = off + (N+1);              // E
  int* pairD = pairS + E;                // E
  int* adj   = pairD + E;                // E

  // weight prep (independent)
  prep_w_kernel<<<dim3(128,6), 256, 0, stream>>>(Wp,Wl0,Wr0,Wl1,Wr1,W1,
                                                 Wpt,Wl0t,Wr0t,Wl1t,Wr1t,W1t);

  // CSR build, coalesced
  hipMemsetAsync(bucketCnt, 0, NBMAX*sizeof(int), stream);
  int gP = (E + EPB - 1) / EPB;   // 196
  bucket_hist_kernel<<<gP, 256, 0, stream>>>(dst, E, NB, bucketCnt);
  scan_buckets_kernel<<<1, NBMAX, 0, stream>>>(bucketCnt, NB, E, bucketBase, bucketCur, off, N);
  partition_kernel<<<gP, 256, 0, stream>>>(src, dst, E, NB, bucketCur, pairS, pairD);
  bucket_csr_kernel<<<NB, 256, 0, stream>>>(bucketBase, pairS, pairD, N, off, adj);

  int gx = (N + 127) / 128;   // 391
  // GEMM0 (A=x fp32, read once): xp = x@Wp+bp ; xl0 = x@Wl0 ; xr0 = x@Wr0
  gemm_mfma_multi<256,3,true><<<gx, 256, 0, stream>>>(x, N, Wpt, Wl0t, Wr0t, bp, xp, xl0, xr0);
  // h = relu(mean(xl0[nbrs]) + bl0 + xr0) + xp
  combine_b_kernel<<<(N+3)/4, 256, 0, stream>>>(xl0, xr0, xp, bl0, off, adj, h, N);

  // GEMM1 (A=h bf16, read once): hl1 = h@Wl1 ; hr1 = h@Wr1
  gemm_mfma_multi<128,2,false><<<gx, 256, 0, stream>>>(h, N, Wl1t, Wr1t, Wr1t, nullptr, xl0, xr0, xr0);
  // h2 = relu(mean(hl1[nbrs]) + bl1 + hr1) + h   (h2 -> xp)
  combine_b_kernel<<<(N+3)/4, 256, 0, stream>>>(xl0, xr0, h, bl1, off, adj, xp, N);

  // head fused: out = a*rer + (1-a)*(relu(xp@W1+b1) . W2 + b2)
  gemm_final_kernel<<<gx, 256, 0, stream>>>(xp, N, W1t, b1, W2, b2, alogit, rer, (float*)d_out);
}